// Round 1
// baseline (1597.590 us; speedup 1.0000x reference)
//
#include <hip/hip_runtime.h>
#include <stdint.h>

#define N_NODES 4096
#define K_NN    40
#define B_CLOUDS 8
#define F_IN    8
#define H_DIM   64
#define O_DIM   128

#define OUT_FEAT_ELEMS (B_CLOUDS * N_NODES * O_DIM)   // 4194304
#define EDGES          (B_CLOUDS * N_NODES * K_NN)    // 1310720

// ---------------------------------------------------------------------------
// Kernel A: exact KNN (matches jax fp32 d2 bitwise + top_k tie-breaking),
// writes edge_index (as float values) into d_out's tail section.
// One wave per target node; 4 targets per 256-thread block; pos cloud in LDS.
// ---------------------------------------------------------------------------
__global__ __launch_bounds__(256) void knn_kernel(const float* __restrict__ pos,
                                                  float* __restrict__ out)
{
    __shared__ float px[N_NODES];
    __shared__ float py[N_NODES];
    __shared__ float pz[N_NODES];

    const int b  = blockIdx.x >> 10;           // 1024 blocks per cloud
    const int i0 = (blockIdx.x & 1023) << 2;   // 4 targets per block
    const float* posb = pos + (size_t)b * N_NODES * 3;

    // Stage positions into LDS as SoA (coalesced global reads).
    for (int t = threadIdx.x; t < N_NODES * 3; t += 256) {
        float v = posb[t];
        int node = t / 3;
        int c = t - node * 3;
        if (c == 0) px[node] = v;
        else if (c == 1) py[node] = v;
        else pz[node] = v;
    }
    __syncthreads();

    const int wave = threadIdx.x >> 6;
    const int lane = threadIdx.x & 63;
    const int i = i0 + wave;

    const float pix = px[i], piy = py[i], piz = pz[i];

    // Sorted-ascending-across-lanes top-64 key array (we need top-40).
    // key = (f32 bits of d2 << 32) | j   -> ascending == (d2 asc, idx asc)
    unsigned long long R = ~0ULL;

    for (int c = 0; c < 64; ++c) {
        const int j = (c << 6) | lane;
        // bitwise-exact fp32: ((dx*dx + dy*dy) + dz*dz), no FMA contraction
        float dx = __fsub_rn(pix, px[j]);
        float dy = __fsub_rn(piy, py[j]);
        float dz = __fsub_rn(piz, pz[j]);
        float d2 = __fadd_rn(__fadd_rn(__fmul_rn(dx, dx), __fmul_rn(dy, dy)),
                             __fmul_rn(dz, dz));
        unsigned long long key =
            ((unsigned long long)__float_as_uint(d2) << 32) | (unsigned)j;
        if (j == i) key = ~0ULL;   // loop=False: exclude self

        unsigned long long r39 = __shfl(R, 39);          // current 40th smallest
        unsigned long long mask = __ballot(key < r39);   // wave-uniform
        while (mask) {
            int src = __builtin_ctzll(mask);
            mask &= mask - 1;
            unsigned long long kb = __shfl(key, src);    // uniform
            r39 = __shfl(R, 39);
            if (kb < r39) {                              // uniform branch
                unsigned long long lt = __ballot(R < kb);
                int p = __popcll(lt);                    // insertion rank
                unsigned long long up = __shfl_up(R, 1);
                R = (lane < p) ? R : ((lane == p) ? kb : up);
            }
        }
    }

    // Emit edges: src = global neighbor id, tgt = global target id (as floats)
    float* src_out = out + OUT_FEAT_ELEMS;
    float* tgt_out = src_out + EDGES;
    const int gi = b * N_NODES + i;
    if (lane < K_NN) {
        int j = (int)(unsigned)(R & 0xFFFFFFFFu);
        src_out[(size_t)gi * K_NN + lane] = (float)(b * N_NODES + j);
        tgt_out[(size_t)gi * K_NN + lane] = (float)gi;
    }
}

// ---------------------------------------------------------------------------
// Kernel B: per-edge MLP (11 -> 64 relu -> 128) + max aggregation.
// One wave per target; lane owns output channels (lane, lane+64); W2 columns
// preloaded in VGPRs; per-neighbor h computed lane-parallel (lane = hidden ch)
// then broadcast via constant-lane shuffles.
// Reads neighbor ids back from the edge section of d_out (written by knn).
// ---------------------------------------------------------------------------
__global__ __launch_bounds__(256, 2) void conv_kernel(
    const float* __restrict__ x, const float* __restrict__ pos,
    const float* __restrict__ W1, const float* __restrict__ b1,
    const float* __restrict__ W2, const float* __restrict__ b2,
    float* __restrict__ out)
{
    __shared__ float msg[4][(K_NN + 1) * 12];   // per-wave message rows (pad 11->12)

    const int b  = blockIdx.x >> 10;
    const int i0 = (blockIdx.x & 1023) << 2;
    const int wave = threadIdx.x >> 6;
    const int lane = threadIdx.x & 63;
    const int i  = i0 + wave;
    const int gi = b * N_NODES + i;

    // Preload weights (coalesced; one-time)
    float w1r[11];
#pragma unroll
    for (int f = 0; f < 11; ++f) w1r[f] = W1[f * H_DIM + lane];
    const float b1r = b1[lane];

    float w2a[64], w2b[64];
#pragma unroll
    for (int k = 0; k < 64; ++k) {
        w2a[k] = W2[k * O_DIM + lane];
        w2b[k] = W2[k * O_DIM + 64 + lane];
    }
    const float b2a = b2[lane], b2b = b2[64 + lane];

    // Phase 1: stage the 41 message rows [x_j(8) | rel(3) | pad]
    const float* src_edges = out + OUT_FEAT_ELEMS;
    if (lane <= K_NN) {
        int j;
        if (lane < K_NN) j = (int)src_edges[(size_t)gi * K_NN + lane] - b * N_NODES;
        else             j = i;   // self loop appended last
        const float* xr = x + ((size_t)b * N_NODES + j) * F_IN;
        float4 xa = *(const float4*)xr;
        float4 xb = *(const float4*)(xr + 4);
        const float* pj = pos + ((size_t)b * N_NODES + j) * 3;
        const float* pi = pos + ((size_t)b * N_NODES + i) * 3;
        float4 rel;
        rel.x = pj[0] - pi[0];
        rel.y = pj[1] - pi[1];
        rel.z = pj[2] - pi[2];
        rel.w = 0.0f;
        float* mrow = &msg[wave][lane * 12];
        *(float4*)(mrow)     = xa;
        *(float4*)(mrow + 4) = xb;
        *(float4*)(mrow + 8) = rel;
    }
    __syncthreads();

    float rmax0 = -3.0e38f, rmax1 = -3.0e38f;

    for (int n = 0; n <= K_NN; ++n) {
        const float* mrow = &msg[wave][n * 12];
        float4 ma = *(const float4*)mrow;        // broadcast LDS reads (free)
        float4 mb = *(const float4*)(mrow + 4);
        float4 mc = *(const float4*)(mrow + 8);

        // layer 1: lane computes hidden channel `lane`
        float h = b1r;
        h = fmaf(ma.x, w1r[0], h);  h = fmaf(ma.y, w1r[1], h);
        h = fmaf(ma.z, w1r[2], h);  h = fmaf(ma.w, w1r[3], h);
        h = fmaf(mb.x, w1r[4], h);  h = fmaf(mb.y, w1r[5], h);
        h = fmaf(mb.z, w1r[6], h);  h = fmaf(mb.w, w1r[7], h);
        h = fmaf(mc.x, w1r[8], h);  h = fmaf(mc.y, w1r[9], h);
        h = fmaf(mc.z, w1r[10], h);
        h = fmaxf(h, 0.0f);

        // layer 2: broadcast h_k, accumulate the lane's two output channels
        float m0 = b2a, m1 = b2b;
#pragma unroll
        for (int k = 0; k < 64; ++k) {
            float hk = __shfl(h, k);   // constant lane -> readlane
            m0 = fmaf(hk, w2a[k], m0);
            m1 = fmaf(hk, w2b[k], m1);
        }
        rmax0 = fmaxf(rmax0, m0);
        rmax1 = fmaxf(rmax1, m1);
    }

    out[(size_t)gi * O_DIM + lane]      = rmax0;
    out[(size_t)gi * O_DIM + 64 + lane] = rmax1;
}

// ---------------------------------------------------------------------------
extern "C" void kernel_launch(void* const* d_in, const int* in_sizes, int n_in,
                              void* d_out, int out_size, void* d_ws, size_t ws_size,
                              hipStream_t stream) {
    const float* x   = (const float*)d_in[0];
    const float* pos = (const float*)d_in[1];
    const float* W1  = (const float*)d_in[2];
    const float* b1  = (const float*)d_in[3];
    const float* W2  = (const float*)d_in[4];
    const float* b2  = (const float*)d_in[5];
    float* out = (float*)d_out;

    const int nblocks = (B_CLOUDS * N_NODES) / 4;   // 8192
    knn_kernel<<<nblocks, 256, 0, stream>>>(pos, out);
    conv_kernel<<<nblocks, 256, 0, stream>>>(x, pos, W1, b1, W2, b2, out);
}

// Round 2
// 806.998 us; speedup vs baseline: 1.9797x; 1.9797x over previous
//
#include <hip/hip_runtime.h>
#include <stdint.h>

#define N_NODES 4096
#define K_NN    40
#define B_CLOUDS 8
#define F_IN    8
#define H_DIM   64
#define O_DIM   128

#define OUT_FEAT_ELEMS (B_CLOUDS * N_NODES * O_DIM)   // 4194304
#define EDGES          (B_CLOUDS * N_NODES * K_NN)    // 1310720

typedef short bf16x8 __attribute__((ext_vector_type(8)));
typedef float f32x4  __attribute__((ext_vector_type(4)));

__device__ __forceinline__ unsigned short f2bf(float f) {
    unsigned u = __float_as_uint(f);
    unsigned r = (u + 0x7FFFu + ((u >> 16) & 1u)) >> 16;   // RNE
    return (unsigned short)r;
}

// ---------------------------------------------------------------------------
// Kernel A: exact KNN — UNCHANGED from R1 (passing; edge absmax 512 < 655).
// ---------------------------------------------------------------------------
__global__ __launch_bounds__(256) void knn_kernel(const float* __restrict__ pos,
                                                  float* __restrict__ out)
{
    __shared__ float px[N_NODES];
    __shared__ float py[N_NODES];
    __shared__ float pz[N_NODES];

    const int b  = blockIdx.x >> 10;
    const int i0 = (blockIdx.x & 1023) << 2;
    const float* posb = pos + (size_t)b * N_NODES * 3;

    for (int t = threadIdx.x; t < N_NODES * 3; t += 256) {
        float v = posb[t];
        int node = t / 3;
        int c = t - node * 3;
        if (c == 0) px[node] = v;
        else if (c == 1) py[node] = v;
        else pz[node] = v;
    }
    __syncthreads();

    const int wave = threadIdx.x >> 6;
    const int lane = threadIdx.x & 63;
    const int i = i0 + wave;

    const float pix = px[i], piy = py[i], piz = pz[i];

    unsigned long long R = ~0ULL;

    for (int c = 0; c < 64; ++c) {
        const int j = (c << 6) | lane;
        float dx = __fsub_rn(pix, px[j]);
        float dy = __fsub_rn(piy, py[j]);
        float dz = __fsub_rn(piz, pz[j]);
        float d2 = __fadd_rn(__fadd_rn(__fmul_rn(dx, dx), __fmul_rn(dy, dy)),
                             __fmul_rn(dz, dz));
        unsigned long long key =
            ((unsigned long long)__float_as_uint(d2) << 32) | (unsigned)j;
        if (j == i) key = ~0ULL;

        unsigned long long r39 = __shfl(R, 39);
        unsigned long long mask = __ballot(key < r39);
        while (mask) {
            int src = __builtin_ctzll(mask);
            mask &= mask - 1;
            unsigned long long kb = __shfl(key, src);
            r39 = __shfl(R, 39);
            if (kb < r39) {
                unsigned long long lt = __ballot(R < kb);
                int p = __popcll(lt);
                unsigned long long up = __shfl_up(R, 1);
                R = (lane < p) ? R : ((lane == p) ? kb : up);
            }
        }
    }

    float* src_out = out + OUT_FEAT_ELEMS;
    float* tgt_out = src_out + EDGES;
    const int gi = b * N_NODES + i;
    if (lane < K_NN) {
        int j = (int)(unsigned)(R & 0xFFFFFFFFu);
        src_out[(size_t)gi * K_NN + lane] = (float)(b * N_NODES + j);
        tgt_out[(size_t)gi * K_NN + lane] = (float)gi;
    }
}

// ---------------------------------------------------------------------------
// Kernel B: per-edge MLP. Layer1 (11->64) fp32 VALU; layer2 (64->128) bf16
// MFMA (48 x v_mfma_f32_16x16x32_bf16 per target). One wave per target.
// H rows 41..47 padded with duplicates of the self row (max-invariant).
// ---------------------------------------------------------------------------
#define HSTR 72   // bf16 row stride for H / W2T: 144 B = 36 words -> 2-way bank (free)

__global__ __launch_bounds__(256, 2) void conv_kernel(
    const float* __restrict__ x, const float* __restrict__ pos,
    const float* __restrict__ W1, const float* __restrict__ b1,
    const float* __restrict__ W2, const float* __restrict__ b2,
    float* __restrict__ out)
{
    __shared__ __align__(16) unsigned short W2T[O_DIM * HSTR];   // 18432 B, [n][k]
    __shared__ __align__(16) unsigned short Hh[4][48 * HSTR];    // 27648 B, [row][k]
    __shared__ __align__(16) float msg[4][(K_NN + 1) * 12];      //  7872 B

    const int b    = blockIdx.x >> 10;
    const int i0   = (blockIdx.x & 1023) << 2;
    const int wave = threadIdx.x >> 6;
    const int lane = threadIdx.x & 63;
    const int quad = lane >> 4;
    const int col  = lane & 15;
    const int i    = i0 + wave;
    const int gi   = b * N_NODES + i;

    // ---- stage W2 transposed as bf16 (once per block, coalesced reads) ----
    for (int t = threadIdx.x; t < H_DIM * O_DIM; t += 256) {
        int k = t >> 7;        // row of W2 (hidden)
        int n = t & 127;       // col of W2 (output channel)
        W2T[n * HSTR + k] = f2bf(W2[t]);
    }

    // ---- stage the 41 message rows [x_j(8) | rel(3) | pad] ----
    const float* src_edges = out + OUT_FEAT_ELEMS;
    if (lane <= K_NN) {
        int j;
        if (lane < K_NN) j = (int)src_edges[(size_t)gi * K_NN + lane] - b * N_NODES;
        else             j = i;   // self loop appended last
        const float* xr = x + ((size_t)b * N_NODES + j) * F_IN;
        float4 xa = *(const float4*)xr;
        float4 xb = *(const float4*)(xr + 4);
        const float* pj = pos + ((size_t)b * N_NODES + j) * 3;
        const float* pi = pos + ((size_t)b * N_NODES + i) * 3;
        float4 rel;
        rel.x = pj[0] - pi[0];
        rel.y = pj[1] - pi[1];
        rel.z = pj[2] - pi[2];
        rel.w = 0.0f;
        float* mrow = &msg[wave][lane * 12];
        *(float4*)(mrow)     = xa;
        *(float4*)(mrow + 4) = xb;
        *(float4*)(mrow + 8) = rel;
    }
    __syncthreads();

    // ---- phase 2: layer1 in fp32, lane = hidden channel; H -> LDS bf16 ----
    float w1r[11];
#pragma unroll
    for (int f = 0; f < 11; ++f) w1r[f] = W1[f * H_DIM + lane];
    const float b1r = b1[lane];

    unsigned short* Hw = Hh[wave];
    float h_last = 0.0f;
#pragma unroll 4
    for (int n = 0; n <= K_NN; ++n) {
        const float* mrow = &msg[wave][n * 12];
        float4 ma = *(const float4*)mrow;
        float4 mb = *(const float4*)(mrow + 4);
        float4 mc = *(const float4*)(mrow + 8);
        float h = b1r;
        h = fmaf(ma.x, w1r[0], h);  h = fmaf(ma.y, w1r[1], h);
        h = fmaf(ma.z, w1r[2], h);  h = fmaf(ma.w, w1r[3], h);
        h = fmaf(mb.x, w1r[4], h);  h = fmaf(mb.y, w1r[5], h);
        h = fmaf(mb.z, w1r[6], h);  h = fmaf(mb.w, w1r[7], h);
        h = fmaf(mc.x, w1r[8], h);  h = fmaf(mc.y, w1r[9], h);
        h = fmaf(mc.z, w1r[10], h);
        h = fmaxf(h, 0.0f);
        Hw[n * HSTR + lane] = f2bf(h);
        h_last = h;
    }
    // pad rows 41..47 with the self row (duplicates; max unchanged)
    {
        unsigned short hb = f2bf(h_last);
#pragma unroll
        for (int r = K_NN + 1; r < 48; ++r) Hw[r * HSTR + lane] = hb;
    }
    __syncthreads();   // cheap insurance: orders LDS writes vs vector reads

    // ---- phase 3: layer2 via MFMA. A frags loaded once, reused over nt ----
    bf16x8 Af[3][2];
#pragma unroll
    for (int mt = 0; mt < 3; ++mt)
#pragma unroll
        for (int kt = 0; kt < 2; ++kt)
            Af[mt][kt] = *(const bf16x8*)&Hw[(mt * 16 + col) * HSTR + kt * 32 + quad * 8];

#pragma unroll
    for (int nt = 0; nt < 8; ++nt) {
        const unsigned short* wrow = &W2T[(nt * 16 + col) * HSTR + quad * 8];
        bf16x8 B0 = *(const bf16x8*)(wrow);
        bf16x8 B1 = *(const bf16x8*)(wrow + 32);

        f32x4 c0 = {0.f, 0.f, 0.f, 0.f};
        f32x4 c1 = {0.f, 0.f, 0.f, 0.f};
        f32x4 c2 = {0.f, 0.f, 0.f, 0.f};
        c0 = __builtin_amdgcn_mfma_f32_16x16x32_bf16(Af[0][0], B0, c0, 0, 0, 0);
        c1 = __builtin_amdgcn_mfma_f32_16x16x32_bf16(Af[1][0], B0, c1, 0, 0, 0);
        c2 = __builtin_amdgcn_mfma_f32_16x16x32_bf16(Af[2][0], B0, c2, 0, 0, 0);
        c0 = __builtin_amdgcn_mfma_f32_16x16x32_bf16(Af[0][1], B1, c0, 0, 0, 0);
        c1 = __builtin_amdgcn_mfma_f32_16x16x32_bf16(Af[1][1], B1, c1, 0, 0, 0);
        c2 = __builtin_amdgcn_mfma_f32_16x16x32_bf16(Af[2][1], B1, c2, 0, 0, 0);

        // max over all 48 rows (pads are duplicates): 12 regs, then cross-quad
        float vm = c0[0];
        vm = fmaxf(vm, c0[1]); vm = fmaxf(vm, c0[2]); vm = fmaxf(vm, c0[3]);
        vm = fmaxf(vm, c1[0]); vm = fmaxf(vm, c1[1]); vm = fmaxf(vm, c1[2]); vm = fmaxf(vm, c1[3]);
        vm = fmaxf(vm, c2[0]); vm = fmaxf(vm, c2[1]); vm = fmaxf(vm, c2[2]); vm = fmaxf(vm, c2[3]);
        vm = fmaxf(vm, __shfl_xor(vm, 16));
        vm = fmaxf(vm, __shfl_xor(vm, 32));
        vm += b2[nt * 16 + col];

        if (lane < 16) out[(size_t)gi * O_DIM + nt * 16 + lane] = vm;
    }
}

// ---------------------------------------------------------------------------
extern "C" void kernel_launch(void* const* d_in, const int* in_sizes, int n_in,
                              void* d_out, int out_size, void* d_ws, size_t ws_size,
                              hipStream_t stream) {
    const float* x   = (const float*)d_in[0];
    const float* pos = (const float*)d_in[1];
    const float* W1  = (const float*)d_in[2];
    const float* b1  = (const float*)d_in[3];
    const float* W2  = (const float*)d_in[4];
    const float* b2  = (const float*)d_in[5];
    float* out = (float*)d_out;

    const int nblocks = (B_CLOUDS * N_NODES) / 4;   // 8192
    knn_kernel<<<nblocks, 256, 0, stream>>>(pos, out);
    conv_kernel<<<nblocks, 256, 0, stream>>>(x, pos, W1, b1, W2, b2, out);
}

// Round 3
// 527.529 us; speedup vs baseline: 3.0284x; 1.5298x over previous
//
#include <hip/hip_runtime.h>
#include <stdint.h>

#define N_NODES 4096
#define K_NN    40
#define B_CLOUDS 8
#define F_IN    8
#define H_DIM   64
#define O_DIM   128

#define OUT_FEAT_ELEMS (B_CLOUDS * N_NODES * O_DIM)   // 4194304
#define EDGES          (B_CLOUDS * N_NODES * K_NN)    // 1310720

typedef short bf16x8 __attribute__((ext_vector_type(8)));
typedef float f32x4  __attribute__((ext_vector_type(4)));

__device__ __forceinline__ unsigned short f2bf(float f) {
    unsigned u = __float_as_uint(f);
    unsigned r = (u + 0x7FFFu + ((u >> 16) & 1u)) >> 16;   // RNE
    return (unsigned short)r;
}

__device__ __forceinline__ unsigned long long readlane_u64(unsigned long long v, int lane) {
    unsigned lo = __builtin_amdgcn_readlane((unsigned)v, lane);
    unsigned hi = __builtin_amdgcn_readlane((unsigned)(v >> 32), lane);
    return ((unsigned long long)hi << 32) | lo;
}

// ---------------------------------------------------------------------------
// Kernel A: exact KNN (bitwise-matching fp32 d2 + top_k tie-break).
// 512 threads = 8 waves = 8 targets per block; pos cloud SoA in 48 KB LDS.
// 3 blocks/CU co-resident -> 24 waves/CU (vs 12 at 256-thread blocks).
// Insertion broadcast via v_readlane (uniform src), scalar threshold guard.
// ---------------------------------------------------------------------------
__global__ __launch_bounds__(512) void knn_kernel(const float* __restrict__ pos,
                                                  float* __restrict__ out)
{
    __shared__ float px[N_NODES];
    __shared__ float py[N_NODES];
    __shared__ float pz[N_NODES];

    const int b  = blockIdx.x >> 9;           // 512 blocks per cloud
    const int i0 = (blockIdx.x & 511) << 3;   // 8 targets per block
    const float* posb = pos + (size_t)b * N_NODES * 3;

    // Stage positions into LDS as SoA (coalesced global reads).
    for (int t = threadIdx.x; t < N_NODES * 3; t += 512) {
        float v = posb[t];
        int node = t / 3;
        int c = t - node * 3;
        if (c == 0) px[node] = v;
        else if (c == 1) py[node] = v;
        else pz[node] = v;
    }
    __syncthreads();

    const int wave = threadIdx.x >> 6;
    const int lane = threadIdx.x & 63;
    const int i = i0 + wave;

    const float pix = px[i], piy = py[i], piz = pz[i];

    // Sorted-ascending-across-lanes top-64 key array (we need top-40).
    // key = (f32 bits of d2 << 32) | j   -> ascending == (d2 asc, idx asc)
    unsigned long long R = ~0ULL;

    for (int c = 0; c < 64; ++c) {
        const int j = (c << 6) | lane;
        // bitwise-exact fp32: ((dx*dx + dy*dy) + dz*dz), no FMA contraction
        float dx = __fsub_rn(pix, px[j]);
        float dy = __fsub_rn(piy, py[j]);
        float dz = __fsub_rn(piz, pz[j]);
        float d2 = __fadd_rn(__fadd_rn(__fmul_rn(dx, dx), __fmul_rn(dy, dy)),
                             __fmul_rn(dz, dz));
        unsigned long long key =
            ((unsigned long long)__float_as_uint(d2) << 32) | (unsigned)j;
        if (j == i) key = ~0ULL;   // loop=False: exclude self

        unsigned long long r39 = readlane_u64(R, 39);    // scalar 40th-smallest
        unsigned long long mask = __ballot(key < r39);   // wave-uniform (SGPR)
        while (mask) {
            int src = __builtin_ctzll(mask);             // uniform
            mask &= mask - 1;
            unsigned long long kb = readlane_u64(key, src);  // SGPR broadcast
            r39 = readlane_u64(R, 39);
            if (kb < r39) {                              // scalar branch
                unsigned long long lt = __ballot(R < kb);
                int p = __popcll(lt);                    // insertion rank
                unsigned long long up = __shfl_up(R, 1);
                R = (lane < p) ? R : ((lane == p) ? kb : up);
            }
        }
    }

    // Emit edges: src = global neighbor id, tgt = global target id (as floats)
    float* src_out = out + OUT_FEAT_ELEMS;
    float* tgt_out = src_out + EDGES;
    const int gi = b * N_NODES + i;
    if (lane < K_NN) {
        int j = (int)(unsigned)(R & 0xFFFFFFFFu);
        src_out[(size_t)gi * K_NN + lane] = (float)(b * N_NODES + j);
        tgt_out[(size_t)gi * K_NN + lane] = (float)gi;
    }
}

// ---------------------------------------------------------------------------
// Kernel B: per-edge MLP. Layer1 (11->64) fp32 VALU; layer2 (64->128) bf16
// MFMA (48 x v_mfma_f32_16x16x32_bf16 per target). One wave per target.
// H rows 41..47 padded with duplicates of the self row (max-invariant).
// UNCHANGED from R2 (994 -> ~148 us).
// ---------------------------------------------------------------------------
#define HSTR 72   // bf16 row stride for H / W2T: 144 B = 36 words -> 2-way bank (free)

__global__ __launch_bounds__(256, 2) void conv_kernel(
    const float* __restrict__ x, const float* __restrict__ pos,
    const float* __restrict__ W1, const float* __restrict__ b1,
    const float* __restrict__ W2, const float* __restrict__ b2,
    float* __restrict__ out)
{
    __shared__ __align__(16) unsigned short W2T[O_DIM * HSTR];   // 18432 B, [n][k]
    __shared__ __align__(16) unsigned short Hh[4][48 * HSTR];    // 27648 B, [row][k]
    __shared__ __align__(16) float msg[4][(K_NN + 1) * 12];      //  7872 B

    const int b    = blockIdx.x >> 10;
    const int i0   = (blockIdx.x & 1023) << 2;
    const int wave = threadIdx.x >> 6;
    const int lane = threadIdx.x & 63;
    const int quad = lane >> 4;
    const int col  = lane & 15;
    const int i    = i0 + wave;
    const int gi   = b * N_NODES + i;

    // ---- stage W2 transposed as bf16 (once per block, coalesced reads) ----
    for (int t = threadIdx.x; t < H_DIM * O_DIM; t += 256) {
        int k = t >> 7;        // row of W2 (hidden)
        int n = t & 127;       // col of W2 (output channel)
        W2T[n * HSTR + k] = f2bf(W2[t]);
    }

    // ---- stage the 41 message rows [x_j(8) | rel(3) | pad] ----
    const float* src_edges = out + OUT_FEAT_ELEMS;
    if (lane <= K_NN) {
        int j;
        if (lane < K_NN) j = (int)src_edges[(size_t)gi * K_NN + lane] - b * N_NODES;
        else             j = i;   // self loop appended last
        const float* xr = x + ((size_t)b * N_NODES + j) * F_IN;
        float4 xa = *(const float4*)xr;
        float4 xb = *(const float4*)(xr + 4);
        const float* pj = pos + ((size_t)b * N_NODES + j) * 3;
        const float* pi = pos + ((size_t)b * N_NODES + i) * 3;
        float4 rel;
        rel.x = pj[0] - pi[0];
        rel.y = pj[1] - pi[1];
        rel.z = pj[2] - pi[2];
        rel.w = 0.0f;
        float* mrow = &msg[wave][lane * 12];
        *(float4*)(mrow)     = xa;
        *(float4*)(mrow + 4) = xb;
        *(float4*)(mrow + 8) = rel;
    }
    __syncthreads();

    // ---- phase 2: layer1 in fp32, lane = hidden channel; H -> LDS bf16 ----
    float w1r[11];
#pragma unroll
    for (int f = 0; f < 11; ++f) w1r[f] = W1[f * H_DIM + lane];
    const float b1r = b1[lane];

    unsigned short* Hw = Hh[wave];
    float h_last = 0.0f;
#pragma unroll 4
    for (int n = 0; n <= K_NN; ++n) {
        const float* mrow = &msg[wave][n * 12];
        float4 ma = *(const float4*)mrow;
        float4 mb = *(const float4*)(mrow + 4);
        float4 mc = *(const float4*)(mrow + 8);
        float h = b1r;
        h = fmaf(ma.x, w1r[0], h);  h = fmaf(ma.y, w1r[1], h);
        h = fmaf(ma.z, w1r[2], h);  h = fmaf(ma.w, w1r[3], h);
        h = fmaf(mb.x, w1r[4], h);  h = fmaf(mb.y, w1r[5], h);
        h = fmaf(mb.z, w1r[6], h);  h = fmaf(mb.w, w1r[7], h);
        h = fmaf(mc.x, w1r[8], h);  h = fmaf(mc.y, w1r[9], h);
        h = fmaf(mc.z, w1r[10], h);
        h = fmaxf(h, 0.0f);
        Hw[n * HSTR + lane] = f2bf(h);
        h_last = h;
    }
    // pad rows 41..47 with the self row (duplicates; max unchanged)
    {
        unsigned short hb = f2bf(h_last);
#pragma unroll
        for (int r = K_NN + 1; r < 48; ++r) Hw[r * HSTR + lane] = hb;
    }
    __syncthreads();

    // ---- phase 3: layer2 via MFMA. A frags loaded once, reused over nt ----
    bf16x8 Af[3][2];
#pragma unroll
    for (int mt = 0; mt < 3; ++mt)
#pragma unroll
        for (int kt = 0; kt < 2; ++kt)
            Af[mt][kt] = *(const bf16x8*)&Hw[(mt * 16 + col) * HSTR + kt * 32 + quad * 8];

#pragma unroll
    for (int nt = 0; nt < 8; ++nt) {
        const unsigned short* wrow = &W2T[(nt * 16 + col) * HSTR + quad * 8];
        bf16x8 B0 = *(const bf16x8*)(wrow);
        bf16x8 B1 = *(const bf16x8*)(wrow + 32);

        f32x4 c0 = {0.f, 0.f, 0.f, 0.f};
        f32x4 c1 = {0.f, 0.f, 0.f, 0.f};
        f32x4 c2 = {0.f, 0.f, 0.f, 0.f};
        c0 = __builtin_amdgcn_mfma_f32_16x16x32_bf16(Af[0][0], B0, c0, 0, 0, 0);
        c1 = __builtin_amdgcn_mfma_f32_16x16x32_bf16(Af[1][0], B0, c1, 0, 0, 0);
        c2 = __builtin_amdgcn_mfma_f32_16x16x32_bf16(Af[2][0], B0, c2, 0, 0, 0);
        c0 = __builtin_amdgcn_mfma_f32_16x16x32_bf16(Af[0][1], B1, c0, 0, 0, 0);
        c1 = __builtin_amdgcn_mfma_f32_16x16x32_bf16(Af[1][1], B1, c1, 0, 0, 0);
        c2 = __builtin_amdgcn_mfma_f32_16x16x32_bf16(Af[2][1], B1, c2, 0, 0, 0);

        // max over all 48 rows (pads are duplicates): 12 regs, then cross-quad
        float vm = c0[0];
        vm = fmaxf(vm, c0[1]); vm = fmaxf(vm, c0[2]); vm = fmaxf(vm, c0[3]);
        vm = fmaxf(vm, c1[0]); vm = fmaxf(vm, c1[1]); vm = fmaxf(vm, c1[2]); vm = fmaxf(vm, c1[3]);
        vm = fmaxf(vm, c2[0]); vm = fmaxf(vm, c2[1]); vm = fmaxf(vm, c2[2]); vm = fmaxf(vm, c2[3]);
        vm = fmaxf(vm, __shfl_xor(vm, 16));
        vm = fmaxf(vm, __shfl_xor(vm, 32));
        vm += b2[nt * 16 + col];

        if (lane < 16) out[(size_t)gi * O_DIM + nt * 16 + lane] = vm;
    }
}

// ---------------------------------------------------------------------------
extern "C" void kernel_launch(void* const* d_in, const int* in_sizes, int n_in,
                              void* d_out, int out_size, void* d_ws, size_t ws_size,
                              hipStream_t stream) {
    const float* x   = (const float*)d_in[0];
    const float* pos = (const float*)d_in[1];
    const float* W1  = (const float*)d_in[2];
    const float* b1  = (const float*)d_in[3];
    const float* W2  = (const float*)d_in[4];
    const float* b2  = (const float*)d_in[5];
    float* out = (float*)d_out;

    knn_kernel<<<(B_CLOUDS * N_NODES) / 8, 512, 0, stream>>>(pos, out);
    conv_kernel<<<(B_CLOUDS * N_NODES) / 4, 256, 0, stream>>>(x, pos, W1, b1, W2, b2, out);
}

// Round 4
// 423.422 us; speedup vs baseline: 3.7730x; 1.2459x over previous
//
#include <hip/hip_runtime.h>
#include <stdint.h>

#define N_NODES 4096
#define K_NN    40
#define B_CLOUDS 8
#define F_IN    8
#define H_DIM   64
#define O_DIM   128

#define OUT_FEAT_ELEMS (B_CLOUDS * N_NODES * O_DIM)   // 4194304
#define EDGES          (B_CLOUDS * N_NODES * K_NN)    // 1310720

typedef short bf16x8 __attribute__((ext_vector_type(8)));
typedef float f32x4  __attribute__((ext_vector_type(4)));

__device__ __forceinline__ unsigned short f2bf(float f) {
    unsigned u = __float_as_uint(f);
    unsigned r = (u + 0x7FFFu + ((u >> 16) & 1u)) >> 16;   // RNE
    return (unsigned short)r;
}

// ---------------------------------------------------------------------------
// Kernel A: exact KNN (bitwise-matching fp32 d2 + lax.top_k tie-break).
// 512 threads = 8 waves = 8 targets per block; pos cloud SoA in 48 KB LDS.
//
// 32-bit key scheme: R = f32 bits of d2 (u32-compare == f32 ordering for
// non-negative values), P = neighbor index payload. Candidates arrive in
// strictly increasing index order, so:
//   - strict ballot (d2 < r39) is exact: an equal-d2 later candidate has a
//     larger index and can never enter the top-40;
//   - stable insertion rank p = popc(R <= kb) preserves (d2, idx) order;
//   - inserts are UNCONDITIONAL for ballot-passing candidates: a candidate
//     stale-qualified by chunk-start r39 lands at rank >= 40 and cannot
//     perturb lanes 0..39 (we keep 64 sorted slots, need only 40).
// ---------------------------------------------------------------------------
__global__ __launch_bounds__(512) void knn_kernel(const float* __restrict__ pos,
                                                  float* __restrict__ out)
{
    __shared__ float px[N_NODES];
    __shared__ float py[N_NODES];
    __shared__ float pz[N_NODES];

    const int b  = blockIdx.x >> 9;           // 512 blocks per cloud
    const int i0 = (blockIdx.x & 511) << 3;   // 8 targets per block
    const float* posb = pos + (size_t)b * N_NODES * 3;

    for (int t = threadIdx.x; t < N_NODES * 3; t += 512) {
        float v = posb[t];
        int node = t / 3;
        int c = t - node * 3;
        if (c == 0) px[node] = v;
        else if (c == 1) py[node] = v;
        else pz[node] = v;
    }
    __syncthreads();

    const int wave = threadIdx.x >> 6;
    const int lane = threadIdx.x & 63;
    const int i = i0 + wave;

    const float pix = px[i], piy = py[i], piz = pz[i];

    unsigned R = 0xFFFFFFFFu;   // sorted-ascending d2 bits across lanes
    unsigned P = 0xFFFFFFFFu;   // neighbor index payload

    for (int c = 0; c < 64; ++c) {
        const int j = (c << 6) | lane;
        // bitwise-exact fp32: ((dx*dx + dy*dy) + dz*dz), no FMA contraction
        float dx = __fsub_rn(pix, px[j]);
        float dy = __fsub_rn(piy, py[j]);
        float dz = __fsub_rn(piz, pz[j]);
        float d2 = __fadd_rn(__fadd_rn(__fmul_rn(dx, dx), __fmul_rn(dy, dy)),
                             __fmul_rn(dz, dz));
        unsigned d2b = __float_as_uint(d2);
        if (j == i) d2b = 0xFFFFFFFFu;   // loop=False: exclude self

        const unsigned r39 = __builtin_amdgcn_readlane(R, 39);  // once per chunk
        unsigned long long mask = __ballot(d2b < r39);
        while (mask) {
            const int src = (int)__builtin_ctzll(mask);
            mask &= mask - 1;
            const unsigned kb = __builtin_amdgcn_readlane(d2b, src);
            const unsigned jj = (unsigned)((c << 6) | src);     // scalar-side
            // stable insertion, unconditional (rank>=40 inserts are harmless)
            unsigned long long le = __ballot(R <= kb);
            const int p = __popcll(le);
            unsigned upR = __shfl_up(R, 1);
            unsigned upP = __shfl_up(P, 1);
            R = (lane < p) ? R : ((lane == p) ? kb : upR);
            P = (lane < p) ? P : ((lane == p) ? jj : upP);
        }
    }

    // Emit edges: src = global neighbor id, tgt = global target id (as floats)
    float* src_out = out + OUT_FEAT_ELEMS;
    float* tgt_out = src_out + EDGES;
    const int gi = b * N_NODES + i;
    if (lane < K_NN) {
        src_out[(size_t)gi * K_NN + lane] = (float)(b * N_NODES + (int)P);
        tgt_out[(size_t)gi * K_NN + lane] = (float)gi;
    }
}

// ---------------------------------------------------------------------------
// Kernel B: per-edge MLP. Layer1 (11->64) fp32 VALU; layer2 (64->128) bf16
// MFMA (48 x v_mfma_f32_16x16x32_bf16 per target). One wave per target.
// H rows 41..47 padded with duplicates of the self row (max-invariant).
// UNCHANGED from R2.
// ---------------------------------------------------------------------------
#define HSTR 72   // bf16 row stride for H / W2T: 144 B = 36 words -> 2-way bank (free)

__global__ __launch_bounds__(256, 2) void conv_kernel(
    const float* __restrict__ x, const float* __restrict__ pos,
    const float* __restrict__ W1, const float* __restrict__ b1,
    const float* __restrict__ W2, const float* __restrict__ b2,
    float* __restrict__ out)
{
    __shared__ __align__(16) unsigned short W2T[O_DIM * HSTR];   // 18432 B, [n][k]
    __shared__ __align__(16) unsigned short Hh[4][48 * HSTR];    // 27648 B, [row][k]
    __shared__ __align__(16) float msg[4][(K_NN + 1) * 12];      //  7872 B

    const int b    = blockIdx.x >> 10;
    const int i0   = (blockIdx.x & 1023) << 2;
    const int wave = threadIdx.x >> 6;
    const int lane = threadIdx.x & 63;
    const int quad = lane >> 4;
    const int col  = lane & 15;
    const int i    = i0 + wave;
    const int gi   = b * N_NODES + i;

    // ---- stage W2 transposed as bf16 (once per block, coalesced reads) ----
    for (int t = threadIdx.x; t < H_DIM * O_DIM; t += 256) {
        int k = t >> 7;        // row of W2 (hidden)
        int n = t & 127;       // col of W2 (output channel)
        W2T[n * HSTR + k] = f2bf(W2[t]);
    }

    // ---- stage the 41 message rows [x_j(8) | rel(3) | pad] ----
    const float* src_edges = out + OUT_FEAT_ELEMS;
    if (lane <= K_NN) {
        int j;
        if (lane < K_NN) j = (int)src_edges[(size_t)gi * K_NN + lane] - b * N_NODES;
        else             j = i;   // self loop appended last
        const float* xr = x + ((size_t)b * N_NODES + j) * F_IN;
        float4 xa = *(const float4*)xr;
        float4 xb = *(const float4*)(xr + 4);
        const float* pj = pos + ((size_t)b * N_NODES + j) * 3;
        const float* pi = pos + ((size_t)b * N_NODES + i) * 3;
        float4 rel;
        rel.x = pj[0] - pi[0];
        rel.y = pj[1] - pi[1];
        rel.z = pj[2] - pi[2];
        rel.w = 0.0f;
        float* mrow = &msg[wave][lane * 12];
        *(float4*)(mrow)     = xa;
        *(float4*)(mrow + 4) = xb;
        *(float4*)(mrow + 8) = rel;
    }
    __syncthreads();

    // ---- phase 2: layer1 in fp32, lane = hidden channel; H -> LDS bf16 ----
    float w1r[11];
#pragma unroll
    for (int f = 0; f < 11; ++f) w1r[f] = W1[f * H_DIM + lane];
    const float b1r = b1[lane];

    unsigned short* Hw = Hh[wave];
    float h_last = 0.0f;
#pragma unroll 4
    for (int n = 0; n <= K_NN; ++n) {
        const float* mrow = &msg[wave][n * 12];
        float4 ma = *(const float4*)mrow;
        float4 mb = *(const float4*)(mrow + 4);
        float4 mc = *(const float4*)(mrow + 8);
        float h = b1r;
        h = fmaf(ma.x, w1r[0], h);  h = fmaf(ma.y, w1r[1], h);
        h = fmaf(ma.z, w1r[2], h);  h = fmaf(ma.w, w1r[3], h);
        h = fmaf(mb.x, w1r[4], h);  h = fmaf(mb.y, w1r[5], h);
        h = fmaf(mb.z, w1r[6], h);  h = fmaf(mb.w, w1r[7], h);
        h = fmaf(mc.x, w1r[8], h);  h = fmaf(mc.y, w1r[9], h);
        h = fmaf(mc.z, w1r[10], h);
        h = fmaxf(h, 0.0f);
        Hw[n * HSTR + lane] = f2bf(h);
        h_last = h;
    }
    // pad rows 41..47 with the self row (duplicates; max unchanged)
    {
        unsigned short hb = f2bf(h_last);
#pragma unroll
        for (int r = K_NN + 1; r < 48; ++r) Hw[r * HSTR + lane] = hb;
    }
    __syncthreads();

    // ---- phase 3: layer2 via MFMA. A frags loaded once, reused over nt ----
    bf16x8 Af[3][2];
#pragma unroll
    for (int mt = 0; mt < 3; ++mt)
#pragma unroll
        for (int kt = 0; kt < 2; ++kt)
            Af[mt][kt] = *(const bf16x8*)&Hw[(mt * 16 + col) * HSTR + kt * 32 + quad * 8];

#pragma unroll
    for (int nt = 0; nt < 8; ++nt) {
        const unsigned short* wrow = &W2T[(nt * 16 + col) * HSTR + quad * 8];
        bf16x8 B0 = *(const bf16x8*)(wrow);
        bf16x8 B1 = *(const bf16x8*)(wrow + 32);

        f32x4 c0 = {0.f, 0.f, 0.f, 0.f};
        f32x4 c1 = {0.f, 0.f, 0.f, 0.f};
        f32x4 c2 = {0.f, 0.f, 0.f, 0.f};
        c0 = __builtin_amdgcn_mfma_f32_16x16x32_bf16(Af[0][0], B0, c0, 0, 0, 0);
        c1 = __builtin_amdgcn_mfma_f32_16x16x32_bf16(Af[1][0], B0, c1, 0, 0, 0);
        c2 = __builtin_amdgcn_mfma_f32_16x16x32_bf16(Af[2][0], B0, c2, 0, 0, 0);
        c0 = __builtin_amdgcn_mfma_f32_16x16x32_bf16(Af[0][1], B1, c0, 0, 0, 0);
        c1 = __builtin_amdgcn_mfma_f32_16x16x32_bf16(Af[1][1], B1, c1, 0, 0, 0);
        c2 = __builtin_amdgcn_mfma_f32_16x16x32_bf16(Af[2][1], B1, c2, 0, 0, 0);

        // max over all 48 rows (pads are duplicates): 12 regs, then cross-quad
        float vm = c0[0];
        vm = fmaxf(vm, c0[1]); vm = fmaxf(vm, c0[2]); vm = fmaxf(vm, c0[3]);
        vm = fmaxf(vm, c1[0]); vm = fmaxf(vm, c1[1]); vm = fmaxf(vm, c1[2]); vm = fmaxf(vm, c1[3]);
        vm = fmaxf(vm, c2[0]); vm = fmaxf(vm, c2[1]); vm = fmaxf(vm, c2[2]); vm = fmaxf(vm, c2[3]);
        vm = fmaxf(vm, __shfl_xor(vm, 16));
        vm = fmaxf(vm, __shfl_xor(vm, 32));
        vm += b2[nt * 16 + col];

        if (lane < 16) out[(size_t)gi * O_DIM + nt * 16 + lane] = vm;
    }
}

// ---------------------------------------------------------------------------
extern "C" void kernel_launch(void* const* d_in, const int* in_sizes, int n_in,
                              void* d_out, int out_size, void* d_ws, size_t ws_size,
                              hipStream_t stream) {
    const float* x   = (const float*)d_in[0];
    const float* pos = (const float*)d_in[1];
    const float* W1  = (const float*)d_in[2];
    const float* b1  = (const float*)d_in[3];
    const float* W2  = (const float*)d_in[4];
    const float* b2  = (const float*)d_in[5];
    float* out = (float*)d_out;

    knn_kernel<<<(B_CLOUDS * N_NODES) / 8, 512, 0, stream>>>(pos, out);
    conv_kernel<<<(B_CLOUDS * N_NODES) / 4, 256, 0, stream>>>(x, pos, W1, b1, W2, b2, out);
}

// Round 9
// 405.116 us; speedup vs baseline: 3.9435x; 1.0452x over previous
//
#include <hip/hip_runtime.h>
#include <stdint.h>

#define N_NODES 4096
#define K_NN    40
#define B_CLOUDS 8
#define F_IN    8
#define H_DIM   64
#define O_DIM   128

#define OUT_FEAT_ELEMS (B_CLOUDS * N_NODES * O_DIM)   // 4194304
#define EDGES          (B_CLOUDS * N_NODES * K_NN)    // 1310720

typedef short bf16x8 __attribute__((ext_vector_type(8)));
typedef float f32x4  __attribute__((ext_vector_type(4)));

__device__ __forceinline__ unsigned short f2bf(float f) {
    unsigned u = __float_as_uint(f);
    unsigned r = (u + 0x7FFFu + ((u >> 16) & 1u)) >> 16;   // RNE
    return (unsigned short)r;
}

// ---------------------------------------------------------------------------
// Kernel A: exact KNN (bitwise-matching fp32 d2 + lax.top_k tie-break).
// 1024 threads = 16 waves = 16 targets per block; pos cloud SoA in 48 KB LDS.
// 2 blocks/CU -> 32 waves/CU (100% wave occupancy).
//
// 32-bit key scheme (R = d2 f32 bits sorted ascending across lanes,
// P = neighbor-index payload). Candidates arrive in strictly increasing
// index order, so:
//   - strict ballot (d2 < r39) is the exact lax.top_k tie-break (an
//     equal-d2 later candidate has a larger index, can never enter top-40);
//   - keep-mask (R <= kb) is a prefix of the sorted array and
//     p = popc(keep) is the stable insertion lane -> ONE rank compare;
//   - shift-up via ds_permute (dest addr hoisted); deposit via a single
//     (lane == p) compare + 2 cndmasks (v_writelane needs 2 SGPR reads and
//     violates the VALU constant-bus limit -- verified R8 compile fail);
//   - inserts are unconditional for ballot-passing candidates: ones staled
//     by within-chunk inserts land at rank >= 40, never touching lanes
//     0..39. Lane 0's undefined shift-in is always masked: if R[0] > kb
//     then p == 0 and the deposit overwrites lane 0.
// ---------------------------------------------------------------------------
__global__ __launch_bounds__(1024) void knn_kernel(const float* __restrict__ pos,
                                                   float* __restrict__ out)
{
    __shared__ float px[N_NODES];
    __shared__ float py[N_NODES];
    __shared__ float pz[N_NODES];

    const int b  = blockIdx.x >> 8;           // 256 blocks per cloud
    const int i0 = (blockIdx.x & 255) << 4;   // 16 targets per block
    const float* posb = pos + (size_t)b * N_NODES * 3;

    for (int t = threadIdx.x; t < N_NODES * 3; t += 1024) {
        float v = posb[t];
        int node = t / 3;
        int c = t - node * 3;
        if (c == 0) px[node] = v;
        else if (c == 1) py[node] = v;
        else pz[node] = v;
    }
    __syncthreads();

    const int wave = threadIdx.x >> 6;
    const int lane = threadIdx.x & 63;
    const int i = i0 + wave;
    const int ci = i >> 6;        // chunk containing self
    const int li = i & 63;        // lane of self within that chunk
    const int up_addr = ((lane + 1) & 63) << 2;   // ds_permute dest addr (hoisted)

    const float pix = px[i], piy = py[i], piz = pz[i];

    unsigned R = 0xFFFFFFFFu;   // sorted-ascending d2 bits across lanes
    unsigned P = 0xFFFFFFFFu;   // neighbor index payload

    for (int c = 0; c < 64; ++c) {
        const int j = (c << 6) | lane;
        // bitwise-exact fp32: ((dx*dx + dy*dy) + dz*dz), no FMA contraction
        float dx = __fsub_rn(pix, px[j]);
        float dy = __fsub_rn(piy, py[j]);
        float dz = __fsub_rn(piz, pz[j]);
        float d2 = __fadd_rn(__fadd_rn(__fmul_rn(dx, dx), __fmul_rn(dy, dy)),
                             __fmul_rn(dz, dz));
        unsigned d2b = __float_as_uint(d2);
        if (c == ci)                       // wave-uniform branch: 1 of 64 chunks
            d2b = (lane == li) ? 0xFFFFFFFFu : d2b;   // loop=False: no self

        const unsigned r39 = (unsigned)__builtin_amdgcn_readlane((int)R, 39);
        unsigned long long mask = __ballot(d2b < r39);
        while (mask) {
            const int src = (int)__builtin_ctzll(mask);
            mask &= mask - 1;
            const unsigned kb = (unsigned)__builtin_amdgcn_readlane((int)d2b, src);
            const unsigned jj = (unsigned)((c << 6) | src);           // SGPR
            const bool keep = (R <= kb);              // captured BEFORE updates
            unsigned long long le = __ballot(keep);
            const int p = (int)__builtin_popcountll(le);
            unsigned upR = (unsigned)__builtin_amdgcn_ds_permute(up_addr, (int)R);
            unsigned upP = (unsigned)__builtin_amdgcn_ds_permute(up_addr, (int)P);
            R = keep ? R : upR;
            P = keep ? P : upP;
            const bool at = (lane == p);              // one cmp, two cndmasks
            R = at ? kb : R;
            P = at ? jj : P;
        }
    }

    // Emit edges: src = global neighbor id, tgt = global target id (as floats)
    float* src_out = out + OUT_FEAT_ELEMS;
    float* tgt_out = src_out + EDGES;
    const int gi = b * N_NODES + i;
    if (lane < K_NN) {
        src_out[(size_t)gi * K_NN + lane] = (float)(b * N_NODES + (int)P);
        tgt_out[(size_t)gi * K_NN + lane] = (float)gi;
    }
}

// ---------------------------------------------------------------------------
// Kernel B: per-edge MLP. Layer1 (11->64) fp32 VALU; layer2 (64->128) bf16
// MFMA (48 x v_mfma_f32_16x16x32_bf16 per target). One wave per target.
// H rows 41..47 padded with duplicates of the self row (max-invariant).
// UNCHANGED from R2.
// ---------------------------------------------------------------------------
#define HSTR 72   // bf16 row stride for H / W2T: 144 B = 36 words -> 2-way bank (free)

__global__ __launch_bounds__(256, 2) void conv_kernel(
    const float* __restrict__ x, const float* __restrict__ pos,
    const float* __restrict__ W1, const float* __restrict__ b1,
    const float* __restrict__ W2, const float* __restrict__ b2,
    float* __restrict__ out)
{
    __shared__ __align__(16) unsigned short W2T[O_DIM * HSTR];   // 18432 B, [n][k]
    __shared__ __align__(16) unsigned short Hh[4][48 * HSTR];    // 27648 B, [row][k]
    __shared__ __align__(16) float msg[4][(K_NN + 1) * 12];      //  7872 B

    const int b    = blockIdx.x >> 10;
    const int i0   = (blockIdx.x & 1023) << 2;
    const int wave = threadIdx.x >> 6;
    const int lane = threadIdx.x & 63;
    const int quad = lane >> 4;
    const int col  = lane & 15;
    const int i    = i0 + wave;
    const int gi   = b * N_NODES + i;

    // ---- stage W2 transposed as bf16 (once per block, coalesced reads) ----
    for (int t = threadIdx.x; t < H_DIM * O_DIM; t += 256) {
        int k = t >> 7;        // row of W2 (hidden)
        int n = t & 127;       // col of W2 (output channel)
        W2T[n * HSTR + k] = f2bf(W2[t]);
    }

    // ---- stage the 41 message rows [x_j(8) | rel(3) | pad] ----
    const float* src_edges = out + OUT_FEAT_ELEMS;
    if (lane <= K_NN) {
        int j;
        if (lane < K_NN) j = (int)src_edges[(size_t)gi * K_NN + lane] - b * N_NODES;
        else             j = i;   // self loop appended last
        const float* xr = x + ((size_t)b * N_NODES + j) * F_IN;
        float4 xa = *(const float4*)xr;
        float4 xb = *(const float4*)(xr + 4);
        const float* pj = pos + ((size_t)b * N_NODES + j) * 3;
        const float* pi = pos + ((size_t)b * N_NODES + i) * 3;
        float4 rel;
        rel.x = pj[0] - pi[0];
        rel.y = pj[1] - pi[1];
        rel.z = pj[2] - pi[2];
        rel.w = 0.0f;
        float* mrow = &msg[wave][lane * 12];
        *(float4*)(mrow)     = xa;
        *(float4*)(mrow + 4) = xb;
        *(float4*)(mrow + 8) = rel;
    }
    __syncthreads();

    // ---- phase 2: layer1 in fp32, lane = hidden channel; H -> LDS bf16 ----
    float w1r[11];
#pragma unroll
    for (int f = 0; f < 11; ++f) w1r[f] = W1[f * H_DIM + lane];
    const float b1r = b1[lane];

    unsigned short* Hw = Hh[wave];
    float h_last = 0.0f;
#pragma unroll 4
    for (int n = 0; n <= K_NN; ++n) {
        const float* mrow = &msg[wave][n * 12];
        float4 ma = *(const float4*)mrow;
        float4 mb = *(const float4*)(mrow + 4);
        float4 mc = *(const float4*)(mrow + 8);
        float h = b1r;
        h = fmaf(ma.x, w1r[0], h);  h = fmaf(ma.y, w1r[1], h);
        h = fmaf(ma.z, w1r[2], h);  h = fmaf(ma.w, w1r[3], h);
        h = fmaf(mb.x, w1r[4], h);  h = fmaf(mb.y, w1r[5], h);
        h = fmaf(mb.z, w1r[6], h);  h = fmaf(mb.w, w1r[7], h);
        h = fmaf(mc.x, w1r[8], h);  h = fmaf(mc.y, w1r[9], h);
        h = fmaf(mc.z, w1r[10], h);
        h = fmaxf(h, 0.0f);
        Hw[n * HSTR + lane] = f2bf(h);
        h_last = h;
    }
    // pad rows 41..47 with the self row (duplicates; max unchanged)
    {
        unsigned short hb = f2bf(h_last);
#pragma unroll
        for (int r = K_NN + 1; r < 48; ++r) Hw[r * HSTR + lane] = hb;
    }
    __syncthreads();

    // ---- phase 3: layer2 via MFMA. A frags loaded once, reused over nt ----
    bf16x8 Af[3][2];
#pragma unroll
    for (int mt = 0; mt < 3; ++mt)
#pragma unroll
        for (int kt = 0; kt < 2; ++kt)
            Af[mt][kt] = *(const bf16x8*)&Hw[(mt * 16 + col) * HSTR + kt * 32 + quad * 8];

#pragma unroll
    for (int nt = 0; nt < 8; ++nt) {
        const unsigned short* wrow = &W2T[(nt * 16 + col) * HSTR + quad * 8];
        bf16x8 B0 = *(const bf16x8*)(wrow);
        bf16x8 B1 = *(const bf16x8*)(wrow + 32);

        f32x4 c0 = {0.f, 0.f, 0.f, 0.f};
        f32x4 c1 = {0.f, 0.f, 0.f, 0.f};
        f32x4 c2 = {0.f, 0.f, 0.f, 0.f};
        c0 = __builtin_amdgcn_mfma_f32_16x16x32_bf16(Af[0][0], B0, c0, 0, 0, 0);
        c1 = __builtin_amdgcn_mfma_f32_16x16x32_bf16(Af[1][0], B0, c1, 0, 0, 0);
        c2 = __builtin_amdgcn_mfma_f32_16x16x32_bf16(Af[2][0], B0, c2, 0, 0, 0);
        c0 = __builtin_amdgcn_mfma_f32_16x16x32_bf16(Af[0][1], B1, c0, 0, 0, 0);
        c1 = __builtin_amdgcn_mfma_f32_16x16x32_bf16(Af[1][1], B1, c1, 0, 0, 0);
        c2 = __builtin_amdgcn_mfma_f32_16x16x32_bf16(Af[2][1], B1, c2, 0, 0, 0);

        // max over all 48 rows (pads are duplicates): 12 regs, then cross-quad
        float vm = c0[0];
        vm = fmaxf(vm, c0[1]); vm = fmaxf(vm, c0[2]); vm = fmaxf(vm, c0[3]);
        vm = fmaxf(vm, c1[0]); vm = fmaxf(vm, c1[1]); vm = fmaxf(vm, c1[2]); vm = fmaxf(vm, c1[3]);
        vm = fmaxf(vm, c2[0]); vm = fmaxf(vm, c2[1]); vm = fmaxf(vm, c2[2]); vm = fmaxf(vm, c2[3]);
        vm = fmaxf(vm, __shfl_xor(vm, 16));
        vm = fmaxf(vm, __shfl_xor(vm, 32));
        vm += b2[nt * 16 + col];

        if (lane < 16) out[(size_t)gi * O_DIM + nt * 16 + lane] = vm;
    }
}

// ---------------------------------------------------------------------------
extern "C" void kernel_launch(void* const* d_in, const int* in_sizes, int n_in,
                              void* d_out, int out_size, void* d_ws, size_t ws_size,
                              hipStream_t stream) {
    const float* x   = (const float*)d_in[0];
    const float* pos = (const float*)d_in[1];
    const float* W1  = (const float*)d_in[2];
    const float* b1  = (const float*)d_in[3];
    const float* W2  = (const float*)d_in[4];
    const float* b2  = (const float*)d_in[5];
    float* out = (float*)d_out;

    knn_kernel<<<(B_CLOUDS * N_NODES) / 16, 1024, 0, stream>>>(pos, out);
    conv_kernel<<<(B_CLOUDS * N_NODES) / 4, 256, 0, stream>>>(x, pos, W1, b1, W2, b2, out);
}

// Round 10
// 350.901 us; speedup vs baseline: 4.5528x; 1.1545x over previous
//
#include <hip/hip_runtime.h>
#include <stdint.h>

#define N_NODES 4096
#define K_NN    40
#define B_CLOUDS 8
#define F_IN    8
#define H_DIM   64
#define O_DIM   128

#define OUT_FEAT_ELEMS (B_CLOUDS * N_NODES * O_DIM)   // 4194304
#define EDGES          (B_CLOUDS * N_NODES * K_NN)    // 1310720

typedef short bf16x8 __attribute__((ext_vector_type(8)));
typedef float f32x4  __attribute__((ext_vector_type(4)));

__device__ __forceinline__ unsigned short f2bf(float f) {
    unsigned u = __float_as_uint(f);
    unsigned r = (u + 0x7FFFu + ((u >> 16) & 1u)) >> 16;   // RNE
    return (unsigned short)r;
}

// ---------------------------------------------------------------------------
// Kernel A: exact KNN — UNCHANGED from R9 (236 us, passing).
// ---------------------------------------------------------------------------
__global__ __launch_bounds__(1024) void knn_kernel(const float* __restrict__ pos,
                                                   float* __restrict__ out)
{
    __shared__ float px[N_NODES];
    __shared__ float py[N_NODES];
    __shared__ float pz[N_NODES];

    const int b  = blockIdx.x >> 8;           // 256 blocks per cloud
    const int i0 = (blockIdx.x & 255) << 4;   // 16 targets per block
    const float* posb = pos + (size_t)b * N_NODES * 3;

    for (int t = threadIdx.x; t < N_NODES * 3; t += 1024) {
        float v = posb[t];
        int node = t / 3;
        int c = t - node * 3;
        if (c == 0) px[node] = v;
        else if (c == 1) py[node] = v;
        else pz[node] = v;
    }
    __syncthreads();

    const int wave = threadIdx.x >> 6;
    const int lane = threadIdx.x & 63;
    const int i = i0 + wave;
    const int ci = i >> 6;        // chunk containing self
    const int li = i & 63;        // lane of self within that chunk
    const int up_addr = ((lane + 1) & 63) << 2;   // ds_permute dest addr (hoisted)

    const float pix = px[i], piy = py[i], piz = pz[i];

    unsigned R = 0xFFFFFFFFu;   // sorted-ascending d2 bits across lanes
    unsigned P = 0xFFFFFFFFu;   // neighbor index payload

    for (int c = 0; c < 64; ++c) {
        const int j = (c << 6) | lane;
        // bitwise-exact fp32: ((dx*dx + dy*dy) + dz*dz), no FMA contraction
        float dx = __fsub_rn(pix, px[j]);
        float dy = __fsub_rn(piy, py[j]);
        float dz = __fsub_rn(piz, pz[j]);
        float d2 = __fadd_rn(__fadd_rn(__fmul_rn(dx, dx), __fmul_rn(dy, dy)),
                             __fmul_rn(dz, dz));
        unsigned d2b = __float_as_uint(d2);
        if (c == ci)                       // wave-uniform branch: 1 of 64 chunks
            d2b = (lane == li) ? 0xFFFFFFFFu : d2b;   // loop=False: no self

        const unsigned r39 = (unsigned)__builtin_amdgcn_readlane((int)R, 39);
        unsigned long long mask = __ballot(d2b < r39);
        while (mask) {
            const int src = (int)__builtin_ctzll(mask);
            mask &= mask - 1;
            const unsigned kb = (unsigned)__builtin_amdgcn_readlane((int)d2b, src);
            const unsigned jj = (unsigned)((c << 6) | src);           // SGPR
            const bool keep = (R <= kb);              // captured BEFORE updates
            unsigned long long le = __ballot(keep);
            const int p = (int)__builtin_popcountll(le);
            unsigned upR = (unsigned)__builtin_amdgcn_ds_permute(up_addr, (int)R);
            unsigned upP = (unsigned)__builtin_amdgcn_ds_permute(up_addr, (int)P);
            R = keep ? R : upR;
            P = keep ? P : upP;
            const bool at = (lane == p);              // one cmp, two cndmasks
            R = at ? kb : R;
            P = at ? jj : P;
        }
    }

    float* src_out = out + OUT_FEAT_ELEMS;
    float* tgt_out = src_out + EDGES;
    const int gi = b * N_NODES + i;
    if (lane < K_NN) {
        src_out[(size_t)gi * K_NN + lane] = (float)(b * N_NODES + (int)P);
        tgt_out[(size_t)gi * K_NN + lane] = (float)gi;
    }
}

// ---------------------------------------------------------------------------
// Kernel P: precompute W2 bf16 B-fragments into d_ws.
// Layout: ws[((nt*2 + kt)*64 + lane)*8 + j] = bf16(W2[kt*32 + (lane>>4)*8 + j]
//                                                    [nt*16 + (lane&15)])
// so conv's per-(nt,kt) B-fragment is ONE coalesced dwordx4 per lane.
// 8192 bf16 = 16 KB, L1-resident during conv.
// ---------------------------------------------------------------------------
__global__ __launch_bounds__(256) void w2prep_kernel(const float* __restrict__ W2,
                                                     unsigned short* __restrict__ ws)
{
    const int idx = blockIdx.x * 256 + threadIdx.x;   // 0..8191
    const int j    = idx & 7;
    const int lane = (idx >> 3) & 63;
    const int kt   = (idx >> 9) & 1;
    const int nt   = idx >> 10;
    const int k = kt * 32 + (lane >> 4) * 8 + j;
    const int n = nt * 16 + (lane & 15);
    ws[idx] = f2bf(W2[k * O_DIM + n]);
}

// ---------------------------------------------------------------------------
// Kernel B: per-edge MLP. Layer1 (11->64) fp32 VALU; layer2 (64->128) bf16
// MFMA. One wave per target. W2 B-frags come from d_ws (global, L1-hot) --
// no W2T LDS, no staging loop, one less barrier. LDS = Hh + msg = 35.5 KB
// -> 4 blocks/CU = 16 waves/CU (was 2 blocks/CU = 8 waves/CU).
// ---------------------------------------------------------------------------
#define HSTR 72   // bf16 row stride for Hh: 144 B = 36 words -> 2-way bank (free)

__global__ __launch_bounds__(256, 4) void conv_kernel(
    const float* __restrict__ x, const float* __restrict__ pos,
    const float* __restrict__ W1, const float* __restrict__ b1,
    const unsigned short* __restrict__ w2f,   // d_ws B-fragments
    const float* __restrict__ b2,
    float* __restrict__ out)
{
    __shared__ __align__(16) unsigned short Hh[4][48 * HSTR];    // 27648 B
    __shared__ __align__(16) float msg[4][(K_NN + 1) * 12];      //  7872 B

    const int b    = blockIdx.x >> 10;
    const int i0   = (blockIdx.x & 1023) << 2;
    const int wave = threadIdx.x >> 6;
    const int lane = threadIdx.x & 63;
    const int quad = lane >> 4;
    const int col  = lane & 15;
    const int i    = i0 + wave;
    const int gi   = b * N_NODES + i;

    // ---- stage the 41 message rows [x_j(8) | rel(3) | pad] ----
    const float* src_edges = out + OUT_FEAT_ELEMS;
    if (lane <= K_NN) {
        int j;
        if (lane < K_NN) j = (int)src_edges[(size_t)gi * K_NN + lane] - b * N_NODES;
        else             j = i;   // self loop appended last
        const float* xr = x + ((size_t)b * N_NODES + j) * F_IN;
        float4 xa = *(const float4*)xr;
        float4 xb = *(const float4*)(xr + 4);
        const float* pj = pos + ((size_t)b * N_NODES + j) * 3;
        const float* pi = pos + ((size_t)b * N_NODES + i) * 3;
        float4 rel;
        rel.x = pj[0] - pi[0];
        rel.y = pj[1] - pi[1];
        rel.z = pj[2] - pi[2];
        rel.w = 0.0f;
        float* mrow = &msg[wave][lane * 12];
        *(float4*)(mrow)     = xa;
        *(float4*)(mrow + 4) = xb;
        *(float4*)(mrow + 8) = rel;
    }
    __syncthreads();

    // ---- phase 2: layer1 in fp32, lane = hidden channel; H -> LDS bf16 ----
    float w1r[11];
#pragma unroll
    for (int f = 0; f < 11; ++f) w1r[f] = W1[f * H_DIM + lane];
    const float b1r = b1[lane];

    unsigned short* Hw = Hh[wave];
    float h_last = 0.0f;
#pragma unroll 4
    for (int n = 0; n <= K_NN; ++n) {
        const float* mrow = &msg[wave][n * 12];
        float4 ma = *(const float4*)mrow;
        float4 mb = *(const float4*)(mrow + 4);
        float4 mc = *(const float4*)(mrow + 8);
        float h = b1r;
        h = fmaf(ma.x, w1r[0], h);  h = fmaf(ma.y, w1r[1], h);
        h = fmaf(ma.z, w1r[2], h);  h = fmaf(ma.w, w1r[3], h);
        h = fmaf(mb.x, w1r[4], h);  h = fmaf(mb.y, w1r[5], h);
        h = fmaf(mb.z, w1r[6], h);  h = fmaf(mb.w, w1r[7], h);
        h = fmaf(mc.x, w1r[8], h);  h = fmaf(mc.y, w1r[9], h);
        h = fmaf(mc.z, w1r[10], h);
        h = fmaxf(h, 0.0f);
        Hw[n * HSTR + lane] = f2bf(h);
        h_last = h;
    }
    // pad rows 41..47 with the self row (duplicates; max unchanged)
    {
        unsigned short hb = f2bf(h_last);
#pragma unroll
        for (int r = K_NN + 1; r < 48; ++r) Hw[r * HSTR + lane] = hb;
    }
    __syncthreads();

    // ---- phase 3: layer2 via MFMA. A frags from LDS; B frags from d_ws ----
    bf16x8 Af[3][2];
#pragma unroll
    for (int mt = 0; mt < 3; ++mt)
#pragma unroll
        for (int kt = 0; kt < 2; ++kt)
            Af[mt][kt] = *(const bf16x8*)&Hw[(mt * 16 + col) * HSTR + kt * 32 + quad * 8];

    const bf16x8* Bws = (const bf16x8*)w2f;
#pragma unroll
    for (int nt = 0; nt < 8; ++nt) {
        bf16x8 B0 = Bws[nt * 128 + lane];        // kt=0 frag (dwordx4, L1-hot)
        bf16x8 B1 = Bws[nt * 128 + 64 + lane];   // kt=1 frag

        f32x4 c0 = {0.f, 0.f, 0.f, 0.f};
        f32x4 c1 = {0.f, 0.f, 0.f, 0.f};
        f32x4 c2 = {0.f, 0.f, 0.f, 0.f};
        c0 = __builtin_amdgcn_mfma_f32_16x16x32_bf16(Af[0][0], B0, c0, 0, 0, 0);
        c1 = __builtin_amdgcn_mfma_f32_16x16x32_bf16(Af[1][0], B0, c1, 0, 0, 0);
        c2 = __builtin_amdgcn_mfma_f32_16x16x32_bf16(Af[2][0], B0, c2, 0, 0, 0);
        c0 = __builtin_amdgcn_mfma_f32_16x16x32_bf16(Af[0][1], B1, c0, 0, 0, 0);
        c1 = __builtin_amdgcn_mfma_f32_16x16x32_bf16(Af[1][1], B1, c1, 0, 0, 0);
        c2 = __builtin_amdgcn_mfma_f32_16x16x32_bf16(Af[2][1], B1, c2, 0, 0, 0);

        // max over all 48 rows (pads are duplicates): 12 regs, then cross-quad
        float vm = c0[0];
        vm = fmaxf(vm, c0[1]); vm = fmaxf(vm, c0[2]); vm = fmaxf(vm, c0[3]);
        vm = fmaxf(vm, c1[0]); vm = fmaxf(vm, c1[1]); vm = fmaxf(vm, c1[2]); vm = fmaxf(vm, c1[3]);
        vm = fmaxf(vm, c2[0]); vm = fmaxf(vm, c2[1]); vm = fmaxf(vm, c2[2]); vm = fmaxf(vm, c2[3]);
        vm = fmaxf(vm, __shfl_xor(vm, 16));
        vm = fmaxf(vm, __shfl_xor(vm, 32));
        vm += b2[nt * 16 + col];

        if (lane < 16) out[(size_t)gi * O_DIM + nt * 16 + lane] = vm;
    }
}

// ---------------------------------------------------------------------------
extern "C" void kernel_launch(void* const* d_in, const int* in_sizes, int n_in,
                              void* d_out, int out_size, void* d_ws, size_t ws_size,
                              hipStream_t stream) {
    const float* x   = (const float*)d_in[0];
    const float* pos = (const float*)d_in[1];
    const float* W1  = (const float*)d_in[2];
    const float* b1  = (const float*)d_in[3];
    const float* W2  = (const float*)d_in[4];
    const float* b2  = (const float*)d_in[5];
    float* out = (float*)d_out;
    unsigned short* w2f = (unsigned short*)d_ws;   // 8192 bf16 = 16 KB

    w2prep_kernel<<<32, 256, 0, stream>>>(W2, w2f);
    knn_kernel<<<(B_CLOUDS * N_NODES) / 16, 1024, 0, stream>>>(pos, out);
    conv_kernel<<<(B_CLOUDS * N_NODES) / 4, 256, 0, stream>>>(x, pos, W1, b1, w2f, b2, out);
}